// Round 11
// baseline (321.257 us; speedup 1.0000x reference)
//
#include <hip/hip_runtime.h>
#include <hip/hip_bf16.h>

// ---- problem constants ----
#define HD 128          // head dim == hidden dim
#define NH 8            // heads
#define SQ 2048         // seq len
#define NROWS 4096      // B*S
#define RSQRT_D 0.08838834764831845f

typedef __bf16 bf16;
typedef bf16 bf16x8 __attribute__((ext_vector_type(8)));
typedef float f32x4 __attribute__((ext_vector_type(4)));

__device__ __forceinline__ f32x4 mfma16(bf16x8 a, bf16x8 b, f32x4 c) {
  return __builtin_amdgcn_mfma_f32_16x16x32_bf16(a, b, c, 0, 0, 0);
}
__device__ __forceinline__ bf16x8 ld8(const bf16* p) { return *(const bf16x8*)p; }
__device__ __forceinline__ unsigned short bfu(float v) {
  return __builtin_bit_cast(unsigned short, (bf16)v);
}
__device__ __forceinline__ unsigned packbf2(float a, float b) {
  return (unsigned)bfu(a) | ((unsigned)bfu(b) << 16);
}

// ---------------- prep: x->bf16, adj->u8 ----------------
__global__ void k_prep_a(const float* __restrict__ x, const int* __restrict__ adj,
                         bf16* __restrict__ xb, unsigned char* __restrict__ mask8) {
  int idx = blockIdx.x * 256 + threadIdx.x;
  if (idx < NROWS * HD) { xb[idx] = (bf16)x[idx]; return; }
  int j = idx - NROWS * HD;
  if (j < (SQ * SQ / 4)) {
    int4 a = ((const int4*)adj)[j];
    uchar4 m;
    m.x = (unsigned char)a.x; m.y = (unsigned char)a.y;
    m.z = (unsigned char)a.z; m.w = (unsigned char)a.w;
    ((uchar4*)mask8)[j] = m;
  }
}

// ---------------- prep: weights -> bf16, [n][k] layout ----------------
__global__ void k_prep_w(const float* __restrict__ Wq, const float* __restrict__ Wk,
                         const float* __restrict__ Wv, const float* __restrict__ Wo,
                         const float* __restrict__ W1, const float* __restrict__ W2,
                         bf16* __restrict__ WqkvT, bf16* __restrict__ WoT,
                         bf16* __restrict__ W1T, bf16* __restrict__ W2T) {
  int idx = blockIdx.x * 256 + threadIdx.x;
  if (idx < 3072 * 128) {
    int n = idx >> 7, kk = idx & 127;
    int sel = n >> 10, nn = n & 1023;
    const float* W = (sel == 0) ? Wq : (sel == 1 ? Wk : Wv);
    WqkvT[idx] = (bf16)W[kk * 1024 + nn];
    return;
  }
  int j = idx - 3072 * 128;
  if (j < 128 * 1024) { int n = j >> 10, kk = j & 1023; WoT[j] = (bf16)Wo[kk * 128 + n]; return; }
  j -= 128 * 1024;
  if (j < 16384) { int n = j >> 7, kk = j & 127; W1T[j] = (bf16)W1[kk * 128 + n]; return; }
  j -= 16384;
  if (j < 16384) { int n = j >> 7, kk = j & 127; W2T[j] = (bf16)W2[kk * 128 + n]; return; }
}

// ---------------- QKV projection GEMM: (4096x128)@(128x3072) ----------------
// q,k written [b][h][s][d] (q pre-scaled by 1/sqrt(D)); v written transposed [b][h][d][s].
__global__ __launch_bounds__(256, 4) void k_qkv(
    const bf16* __restrict__ xb, const bf16* __restrict__ WqkvT,
    const float* __restrict__ bq, const float* __restrict__ bk, const float* __restrict__ bv,
    bf16* __restrict__ qT, bf16* __restrict__ kT, bf16* __restrict__ vT) {
  const int bid = blockIdx.x;
  const int m0 = (bid & 63) << 6;
  const int n0 = (bid >> 6) << 6;
  const int tid = threadIdx.x;
  const int w = tid >> 6, lane = tid & 63, lo = lane & 15, hi = lane >> 4;
  const int mw = m0 + ((w >> 1) << 5);
  const int nw = n0 + ((w & 1) << 5);
  bf16x8 av[2][4], bw[2][4];
#pragma unroll
  for (int ms = 0; ms < 2; ++ms)
#pragma unroll
    for (int ks = 0; ks < 4; ++ks)
      av[ms][ks] = ld8(xb + (size_t)(mw + ms * 16 + lo) * 128 + ks * 32 + hi * 8);
#pragma unroll
  for (int ns = 0; ns < 2; ++ns)
#pragma unroll
    for (int ks = 0; ks < 4; ++ks)
      bw[ns][ks] = ld8(WqkvT + (size_t)(nw + ns * 16 + lo) * 128 + ks * 32 + hi * 8);
  const f32x4 z4 = {0.f, 0.f, 0.f, 0.f};
  f32x4 acc[2][2] = {{z4, z4}, {z4, z4}};
#pragma unroll
  for (int ms = 0; ms < 2; ++ms)
#pragma unroll
    for (int ns = 0; ns < 2; ++ns)
#pragma unroll
      for (int ks = 0; ks < 4; ++ks)
        acc[ms][ns] = mfma16(av[ms][ks], bw[ns][ks], acc[ms][ns]);
#pragma unroll
  for (int ns = 0; ns < 2; ++ns) {
    const int n = nw + ns * 16 + lo;
    const int sel = n >> 10, nn = n & 1023;
    const float bia = (sel == 0 ? bq : sel == 1 ? bk : bv)[nn];
    const int hh = nn >> 7, d = nn & 127;
#pragma unroll
    for (int ms = 0; ms < 2; ++ms) {
      const int mb = mw + ms * 16 + hi * 4;
      const int bb = mb >> 11, s = mb & 2047;
      if (sel == 0) {
#pragma unroll
        for (int r = 0; r < 4; ++r)
          qT[(size_t)((bb * 8 + hh) * 2048 + s + r) * 128 + d] =
              (bf16)((acc[ms][ns][r] + bia) * RSQRT_D);
      } else if (sel == 1) {
#pragma unroll
        for (int r = 0; r < 4; ++r)
          kT[(size_t)((bb * 8 + hh) * 2048 + s + r) * 128 + d] = (bf16)(acc[ms][ns][r] + bia);
      } else {
        ushort4 pk;
        pk.x = bfu(acc[ms][ns][0] + bia);
        pk.y = bfu(acc[ms][ns][1] + bia);
        pk.z = bfu(acc[ms][ns][2] + bia);
        pk.w = bfu(acc[ms][ns][3] + bia);
        *(ushort4*)(vT + (size_t)((bb * 8 + hh) * 128 + d) * 2048 + s) = pk;
      }
    }
  }
}

// ---------------- single-pass flash: Oc + 1/rowsum (NO attn materialization) ----------------
// grid 1024 = 16 (b,h) x 64 q-tiles of 32 rows; 256 threads = 4 waves; wave w owns kv
// slice [w*512,(w+1)*512) for both q-subtiles (af/vf shared across 2 qs = 2:1 economy).
// Per 32-kv chunk: QK^T -> exp -> ssum (f32) + stash bf16 P~ into 1KB wave chunk -> PV.
// Small LDS (17KB) -> occupancy register-bound (~12 waves/CU), no store stream in FIFO.
// Writes normalized Oc and rsums = 1/sum for the materialization kernel.
__global__ __launch_bounds__(256) void k_flash(
    const bf16* __restrict__ qT, const bf16* __restrict__ kT,
    const bf16* __restrict__ vT, const unsigned char* __restrict__ mask8,
    float* __restrict__ rsums, bf16* __restrict__ Oc) {
  __shared__ __align__(16) char smem[17024];  // [0,16K): stash(8K)/Op(16K) union; red 512B; red2 128B
  float* red  = (float*)(smem + 16384);
  float* red2 = (float*)(smem + 16896);

  // XCD-aware bijective swizzle: XCD x gets 128 consecutive works = exactly 2 (b,h) pairs.
  const int lbid = blockIdx.x;
  const int work = ((lbid & 7) << 7) + (lbid >> 3);
  const int bh = work >> 6;
  const int q0 = (work & 63) << 5;
  const int b = bh >> 3, h = bh & 7;
  const int tid = threadIdx.x;
  const int w = tid >> 6, lane = tid & 63, lo = lane & 15, hi = lane >> 4;
  const int kv0 = w * 512;

  const bf16* Qh = qT + (size_t)bh * SQ * HD;
  const bf16* Kh = kT + (size_t)bh * SQ * HD;
  const bf16* Vh = vT + (size_t)bh * HD * SQ;

  bf16x8 qf[2][4];                           // 32 q rows (pre-scaled by 1/sqrt(D))
#pragma unroll
  for (int qs = 0; qs < 2; ++qs)
#pragma unroll
    for (int ks = 0; ks < 4; ++ks)
      qf[qs][ks] = ld8(Qh + (size_t)(q0 + qs * 16 + lo) * HD + ks * 32 + hi * 8);

  const f32x4 z4 = {0.f, 0.f, 0.f, 0.f};
  f32x4 acc[2][8];
#pragma unroll
  for (int qs = 0; qs < 2; ++qs)
#pragma unroll
    for (int ds = 0; ds < 8; ++ds) acc[qs][ds] = z4;
  float ssum0 = 0.f, ssum1 = 0.f;

  for (int i = 0; i < 16; ++i) {
    const int kvA = kv0 + i * 32;
#pragma unroll
    for (int t = 0; t < 2; ++t) {
      const int kvt = kvA + t * 16;
      bf16x8 af[4];
#pragma unroll
      for (int ks = 0; ks < 4; ++ks)
        af[ks] = ld8(Kh + (size_t)(kvt + lo) * HD + ks * 32 + hi * 8);
#pragma unroll
      for (int qs = 0; qs < 2; ++qs) {
        f32x4 c = z4;
#pragma unroll
        for (int ks = 0; ks < 4; ++ks) c = mfma16(af[ks], qf[qs][ks], c);
        const unsigned mu = *(const unsigned*)(mask8 + (size_t)(q0 + qs * 16 + lo) * SQ + kvt + hi * 4);
        float p0 = __expf(c[0] * (0.5f + 0.5f * (float)(mu & 0xff)));
        float p1 = __expf(c[1] * (0.5f + 0.5f * (float)((mu >> 8) & 0xff)));
        float p2 = __expf(c[2] * (0.5f + 0.5f * (float)((mu >> 16) & 0xff)));
        float p3 = __expf(c[3] * (0.5f + 0.5f * (float)((mu >> 24) & 0xff)));
        if (qs == 0) ssum0 += (p0 + p1) + (p2 + p3);
        else         ssum1 += (p0 + p1) + (p2 + p3);
        // stash P~ bf16 into wave-private chunk for the PV lane transpose
        char* stq = smem + (w * 2 + qs) * 1024;
        *(uint2*)(stq + lo * 64 + ((t * 32 + hi * 8) ^ ((lo & 3) << 4))) =
            make_uint2(packbf2(p0, p1), packbf2(p2, p3));
      }
    }
    bf16x8 pa[2];
#pragma unroll
    for (int qs = 0; qs < 2; ++qs) {
      char* stq = smem + (w * 2 + qs) * 1024;
      pa[qs] = *(const bf16x8*)(stq + lo * 64 + ((hi * 16) ^ ((lo & 3) << 4)));
    }
#pragma unroll
    for (int ds = 0; ds < 8; ++ds) {
      bf16x8 vf = ld8(Vh + (size_t)(ds * 16 + lo) * SQ + kvA + hi * 8);
      acc[0][ds] = mfma16(pa[0], vf, acc[0][ds]);
      acc[1][ds] = mfma16(pa[1], vf, acc[1][ds]);
    }
  }

  // ---- softmax denominators: wave slice sums -> block total -> rsums ----
  ssum0 += __shfl_xor(ssum0, 16); ssum0 += __shfl_xor(ssum0, 32);
  ssum1 += __shfl_xor(ssum1, 16); ssum1 += __shfl_xor(ssum1, 32);
  if (hi == 0) { red[w * 32 + lo] = ssum0; red[w * 32 + 16 + lo] = ssum1; }
  __syncthreads();
  if (tid < 32) {
    float t = red[tid] + red[32 + tid] + red[64 + tid] + red[96 + tid];
    const float inv = 1.0f / t;
    red2[tid] = inv;
    rsums[(size_t)bh * SQ + q0 + tid] = inv;
  }
  __syncthreads();

  // ---- cross-wave O reduction in 4 d-chunks of 32; Oc normalized ----
  float* Op = (float*)smem;                  // [4 waves][32 q][32 d] f32 per chunk
#pragma unroll
  for (int dc = 0; dc < 4; ++dc) {
#pragma unroll
    for (int qs = 0; qs < 2; ++qs)
#pragma unroll
      for (int dsl = 0; dsl < 2; ++dsl) {
#pragma unroll
        for (int r = 0; r < 4; ++r)
          Op[w * 1024 + (qs * 16 + hi * 4 + r) * 32 + dsl * 16 + lo] = acc[qs][dc * 2 + dsl][r];
      }
    __syncthreads();
#pragma unroll
    for (int k = 0; k < 4; ++k) {
      const int e = k * 256 + tid;
      const int q = e >> 5, d = e & 31;
      const float sum = Op[q * 32 + d] + Op[1024 + q * 32 + d] +
                        Op[2048 + q * 32 + d] + Op[3072 + q * 32 + d];
      Oc[(size_t)(b * SQ + q0 + q) * (NH * HD) + h * HD + dc * 32 + d] =
          (bf16)(sum * red2[q]);
    }
    __syncthreads();
  }
}

// ---------------- attn materialization: recompute QK^T, scale, stream out ----------------
// grid 1024 = 16 (b,h) x 64 q-tiles of 32 rows; 512 threads = 8 waves; wave w owns kv
// slice [w*256,(w+1)*256) for both q-subtiles (af shared = 2:1 economy). No LDS, no acc,
// low VGPR -> 5-8 waves/SIMD: TLP hides K-load latency; write-BW-bound by design.
__global__ __launch_bounds__(512) void k_awrite(
    const bf16* __restrict__ qT, const bf16* __restrict__ kT,
    const unsigned char* __restrict__ mask8, const float* __restrict__ rsums,
    float* __restrict__ attn_out) {
  // XCD-aware bijective swizzle (same mapping as k_flash).
  const int lbid = blockIdx.x;
  const int work = ((lbid & 7) << 7) + (lbid >> 3);
  const int bh = work >> 6;
  const int q0 = (work & 63) << 5;
  const int tid = threadIdx.x;
  const int w = tid >> 6, lane = tid & 63, lo = lane & 15, hi = lane >> 4;
  const int kv0 = w * 256;

  const bf16* Qh = qT + (size_t)bh * SQ * HD;
  const bf16* Kh = kT + (size_t)bh * SQ * HD;
  const unsigned char* mrow0 = mask8 + (size_t)(q0 + lo) * SQ;
  const unsigned char* mrow1 = mask8 + (size_t)(q0 + 16 + lo) * SQ;
  const float rq0 = rsums[(size_t)bh * SQ + q0 + lo];
  const float rq1 = rsums[(size_t)bh * SQ + q0 + 16 + lo];
  float* abase = attn_out + (size_t)bh * SQ * SQ;

  bf16x8 qf[2][4];
#pragma unroll
  for (int qs = 0; qs < 2; ++qs)
#pragma unroll
    for (int ks = 0; ks < 4; ++ks)
      qf[qs][ks] = ld8(Qh + (size_t)(q0 + qs * 16 + lo) * HD + ks * 32 + hi * 8);

  const f32x4 z4 = {0.f, 0.f, 0.f, 0.f};
#pragma unroll 2
  for (int t = 0; t < 16; ++t) {
    const int kvt = kv0 + t * 16;
    bf16x8 af[4];
#pragma unroll
    for (int ks = 0; ks < 4; ++ks)
      af[ks] = ld8(Kh + (size_t)(kvt + lo) * HD + ks * 32 + hi * 8);
    const unsigned mu0 = *(const unsigned*)(mrow0 + kvt + hi * 4);
    const unsigned mu1 = *(const unsigned*)(mrow1 + kvt + hi * 4);
#pragma unroll
    for (int qs = 0; qs < 2; ++qs) {
      f32x4 c = z4;
#pragma unroll
      for (int ks = 0; ks < 4; ++ks) c = mfma16(af[ks], qf[qs][ks], c);
      const unsigned mu = qs == 0 ? mu0 : mu1;
      const float rinv = qs == 0 ? rq0 : rq1;
      f32x4 o;
      o[0] = __expf(c[0] * (0.5f + 0.5f * (float)(mu & 0xff))) * rinv;
      o[1] = __expf(c[1] * (0.5f + 0.5f * (float)((mu >> 8) & 0xff))) * rinv;
      o[2] = __expf(c[2] * (0.5f + 0.5f * (float)((mu >> 16) & 0xff))) * rinv;
      o[3] = __expf(c[3] * (0.5f + 0.5f * (float)((mu >> 24) & 0xff))) * rinv;
      *(f32x4*)(abase + (size_t)(q0 + qs * 16 + lo) * SQ + kvt + hi * 4) = o;
    }
  }
}

// ---------------- out@Wo + bo + x -> LayerNorm1 -> h (f32 + bf16) ----------------
__global__ __launch_bounds__(256, 4) void k_owo(
    const bf16* __restrict__ Oc, const bf16* __restrict__ WoT,
    const float* __restrict__ bo, const float* __restrict__ x,
    const float* __restrict__ g1, const float* __restrict__ be1,
    float* __restrict__ hf, bf16* __restrict__ hb) {
  __shared__ __align__(16) float hbuf[16 * 128];
  const int m0 = blockIdx.x * 16;
  const int tid = threadIdx.x;
  const int w = tid >> 6, lane = tid & 63, lo = lane & 15, hi = lane >> 4;
  const int nw = w * 32;
  const f32x4 z4 = {0.f, 0.f, 0.f, 0.f};
  f32x4 acc[2] = {z4, z4};
#pragma unroll 4
  for (int kk = 0; kk < 32; ++kk) {
    bf16x8 a = ld8(Oc + (size_t)(m0 + lo) * 1024 + kk * 32 + hi * 8);
#pragma unroll
    for (int ns = 0; ns < 2; ++ns) {
      bf16x8 bb = ld8(WoT + (size_t)(nw + ns * 16 + lo) * 1024 + kk * 32 + hi * 8);
      acc[ns] = mfma16(a, bb, acc[ns]);
    }
  }
#pragma unroll
  for (int ns = 0; ns < 2; ++ns) {
    const int n = nw + ns * 16 + lo;
    const float bia = bo[n];
#pragma unroll
    for (int r = 0; r < 4; ++r) {
      const int mr = hi * 4 + r;
      hbuf[mr * 128 + n] = acc[ns][r] + bia + x[(size_t)(m0 + mr) * 128 + n];
    }
  }
  __syncthreads();
  const float2 g = *(const float2*)(g1 + lane * 2);
  const float2 be = *(const float2*)(be1 + lane * 2);
#pragma unroll
  for (int rr = 0; rr < 4; ++rr) {
    const int row = w * 4 + rr;
    float2 v = *(float2*)&hbuf[row * 128 + lane * 2];
    float s = v.x + v.y, sq = v.x * v.x + v.y * v.y;
#pragma unroll
    for (int off = 32; off; off >>= 1) { s += __shfl_xor(s, off); sq += __shfl_xor(sq, off); }
    const float mean = s * (1.f / 128.f);
    const float var = sq * (1.f / 128.f) - mean * mean;
    const float rstd = rsqrtf(var + 1e-5f);
    const float y0 = (v.x - mean) * rstd * g.x + be.x;
    const float y1 = (v.y - mean) * rstd * g.y + be.y;
    const size_t o = (size_t)(m0 + row) * 128 + lane * 2;
    *(float2*)(hf + o) = make_float2(y0, y1);
    *(unsigned*)(hb + o) = packbf2(y0, y1);
  }
}

// ---------------- FFN (relu(h@W1+b1)@W2+b2) + residual -> LayerNorm2 -> y ----------------
__global__ __launch_bounds__(256, 4) void k_ffn(
    const bf16* __restrict__ hb, const float* __restrict__ hf,
    const bf16* __restrict__ W1T, const bf16* __restrict__ W2T,
    const float* __restrict__ b1, const float* __restrict__ b2,
    const float* __restrict__ g2, const float* __restrict__ be2,
    float* __restrict__ yout) {
  __shared__ __align__(16) bf16 s1[16 * 136];   // +8 pad per row: conflict-free b128 rereads
  __shared__ __align__(16) float ybuf[16 * 128];
  const int m0 = blockIdx.x * 16;
  const int tid = threadIdx.x;
  const int w = tid >> 6, lane = tid & 63, lo = lane & 15, hi = lane >> 4;
  const int nw = w * 32;
  const f32x4 z4 = {0.f, 0.f, 0.f, 0.f};
  f32x4 a1[2] = {z4, z4};
#pragma unroll
  for (int kk = 0; kk < 4; ++kk) {
    bf16x8 a = ld8(hb + (size_t)(m0 + lo) * 128 + kk * 32 + hi * 8);
#pragma unroll
    for (int ns = 0; ns < 2; ++ns)
      a1[ns] = mfma16(a, ld8(W1T + (size_t)(nw + ns * 16 + lo) * 128 + kk * 32 + hi * 8), a1[ns]);
  }
#pragma unroll
  for (int ns = 0; ns < 2; ++ns) {
    const int n = nw + ns * 16 + lo;
    const float bia = b1[n];
#pragma unroll
    for (int r = 0; r < 4; ++r)
      s1[(hi * 4 + r) * 136 + n] = (bf16)fmaxf(a1[ns][r] + bia, 0.f);
  }
  __syncthreads();
  f32x4 a2[2] = {z4, z4};
#pragma unroll
  for (int kk = 0; kk < 4; ++kk) {
    bf16x8 a = *(const bf16x8*)&s1[lo * 136 + kk * 32 + hi * 8];
#pragma unroll
    for (int ns = 0; ns < 2; ++ns)
      a2[ns] = mfma16(a, ld8(W2T + (size_t)(nw + ns * 16 + lo) * 128 + kk * 32 + hi * 8), a2[ns]);
  }
#pragma unroll
  for (int ns = 0; ns < 2; ++ns) {
    const int n = nw + ns * 16 + lo;
    const float bia = b2[n];
#pragma unroll
    for (int r = 0; r < 4; ++r) {
      const int mr = hi * 4 + r;
      ybuf[mr * 128 + n] = a2[ns][r] + bia + hf[(size_t)(m0 + mr) * 128 + n];
    }
  }
  __syncthreads();
  const float2 g = *(const float2*)(g2 + lane * 2);
  const float2 be = *(const float2*)(be2 + lane * 2);
#pragma unroll
  for (int rr = 0; rr < 4; ++rr) {
    const int row = w * 4 + rr;
    float2 v = *(float2*)&ybuf[row * 128 + lane * 2];
    float s = v.x + v.y, sq = v.x * v.x + v.y * v.y;
#pragma unroll
    for (int off = 32; off; off >>= 1) { s += __shfl_xor(s, off); sq += __shfl_xor(sq, off); }
    const float mean = s * (1.f / 128.f);
    const float var = sq * (1.f / 128.f) - mean * mean;
    const float rstd = rsqrtf(var + 1e-5f);
    const float y0 = (v.x - mean) * rstd * g.x + be.x;
    const float y1 = (v.y - mean) * rstd * g.y + be.y;
    *(float2*)(yout + (size_t)(m0 + row) * 128 + lane * 2) = make_float2(y0, y1);
  }
}

extern "C" void kernel_launch(void* const* d_in, const int* in_sizes, int n_in,
                              void* d_out, int out_size, void* d_ws, size_t ws_size,
                              hipStream_t stream) {
  const float* x  = (const float*)d_in[0];
  const int* adj  = (const int*)d_in[1];
  const float* Wq = (const float*)d_in[2];  const float* bq = (const float*)d_in[3];
  const float* Wk = (const float*)d_in[4];  const float* bk = (const float*)d_in[5];
  const float* Wv = (const float*)d_in[6];  const float* bv = (const float*)d_in[7];
  const float* Wo = (const float*)d_in[8];  const float* bo = (const float*)d_in[9];
  const float* g1 = (const float*)d_in[10]; const float* be1 = (const float*)d_in[11];
  const float* g2 = (const float*)d_in[12]; const float* be2 = (const float*)d_in[13];
  const float* W1 = (const float*)d_in[14]; const float* b1 = (const float*)d_in[15];
  const float* W2 = (const float*)d_in[16]; const float* b2 = (const float*)d_in[17];

  char* ws = (char*)d_ws;
  bf16* xb     = (bf16*)(ws + 0);
  bf16* WqkvT  = (bf16*)(ws + 1048576);
  bf16* WoT    = (bf16*)(ws + 1835008);
  bf16* W1T    = (bf16*)(ws + 2097152);
  bf16* W2T    = (bf16*)(ws + 2129920);
  unsigned char* mask8 = (unsigned char*)(ws + 2162688);
  bf16* qT     = (bf16*)(ws + 6356992);
  bf16* kT     = (bf16*)(ws + 14745600);
  bf16* vT     = (bf16*)(ws + 23134208);
  bf16* Oc     = (bf16*)(ws + 31522816);
  float* hf    = (float*)(ws + 39911424);
  bf16* hb     = (bf16*)(ws + 42008576);
  float* rsums = (float*)(ws + 43057152);   // 16*2048 f32 = 128KB

  float* yout = (float*)d_out;
  float* attn_out = yout + (size_t)NROWS * HD;  // y first (524288 f32), then attn

  k_prep_a<<<6144, 256, 0, stream>>>(x, adj, xb, mask8);
  k_prep_w<<<2176, 256, 0, stream>>>(Wq, Wk, Wv, Wo, W1, W2, WqkvT, WoT, W1T, W2T);
  k_qkv<<<3072, 256, 0, stream>>>(xb, WqkvT, bq, bk, bv, qT, kT, vT);
  k_flash<<<1024, 256, 0, stream>>>(qT, kT, vT, mask8, rsums, Oc);
  k_awrite<<<1024, 512, 0, stream>>>(qT, kT, mask8, rsums, attn_out);
  k_owo<<<256, 256, 0, stream>>>(Oc, WoT, bo, x, g1, be1, hf, hb);
  k_ffn<<<256, 256, 0, stream>>>(hb, hf, W1T, W2T, b1, b2, g2, be2, yout);
}

// Round 12
// 225.957 us; speedup vs baseline: 1.4218x; 1.4218x over previous
//
#include <hip/hip_runtime.h>
#include <hip/hip_bf16.h>

// ---- problem constants ----
#define HD 128          // head dim == hidden dim
#define NH 8            // heads
#define SQ 2048         // seq len
#define NROWS 4096      // B*S
#define RSQRT_D 0.08838834764831845f

typedef __bf16 bf16;
typedef bf16 bf16x8 __attribute__((ext_vector_type(8)));
typedef float f32x4 __attribute__((ext_vector_type(4)));

__device__ __forceinline__ f32x4 mfma16(bf16x8 a, bf16x8 b, f32x4 c) {
  return __builtin_amdgcn_mfma_f32_16x16x32_bf16(a, b, c, 0, 0, 0);
}
__device__ __forceinline__ bf16x8 ld8(const bf16* p) { return *(const bf16x8*)p; }
__device__ __forceinline__ unsigned short bfu(float v) {
  return __builtin_bit_cast(unsigned short, (bf16)v);
}
__device__ __forceinline__ unsigned packbf2(float a, float b) {
  return (unsigned)bfu(a) | ((unsigned)bfu(b) << 16);
}
// async global->LDS, 16B/lane; LDS dest = uniform base + lane*16 (linear);
// global src is PER-LANE (pre-swizzle the source to realize swizzled LDS layouts).
__device__ __forceinline__ void gload_lds16(const void* g, void* l) {
  __builtin_amdgcn_global_load_lds(
      (const __attribute__((address_space(1))) void*)g,
      (__attribute__((address_space(3))) void*)l, 16, 0, 0);
}

// ---------------- prep: x->bf16, adj->u8 ----------------
__global__ void k_prep_a(const float* __restrict__ x, const int* __restrict__ adj,
                         bf16* __restrict__ xb, unsigned char* __restrict__ mask8) {
  int idx = blockIdx.x * 256 + threadIdx.x;
  if (idx < NROWS * HD) { xb[idx] = (bf16)x[idx]; return; }
  int j = idx - NROWS * HD;
  if (j < (SQ * SQ / 4)) {
    int4 a = ((const int4*)adj)[j];
    uchar4 m;
    m.x = (unsigned char)a.x; m.y = (unsigned char)a.y;
    m.z = (unsigned char)a.z; m.w = (unsigned char)a.w;
    ((uchar4*)mask8)[j] = m;
  }
}

// ---------------- prep: weights -> bf16, [n][k] layout ----------------
__global__ void k_prep_w(const float* __restrict__ Wq, const float* __restrict__ Wk,
                         const float* __restrict__ Wv, const float* __restrict__ Wo,
                         const float* __restrict__ W1, const float* __restrict__ W2,
                         bf16* __restrict__ WqkvT, bf16* __restrict__ WoT,
                         bf16* __restrict__ W1T, bf16* __restrict__ W2T) {
  int idx = blockIdx.x * 256 + threadIdx.x;
  if (idx < 3072 * 128) {
    int n = idx >> 7, kk = idx & 127;
    int sel = n >> 10, nn = n & 1023;
    const float* W = (sel == 0) ? Wq : (sel == 1 ? Wk : Wv);
    WqkvT[idx] = (bf16)W[kk * 1024 + nn];
    return;
  }
  int j = idx - 3072 * 128;
  if (j < 128 * 1024) { int n = j >> 10, kk = j & 1023; WoT[j] = (bf16)Wo[kk * 128 + n]; return; }
  j -= 128 * 1024;
  if (j < 16384) { int n = j >> 7, kk = j & 127; W1T[j] = (bf16)W1[kk * 128 + n]; return; }
  j -= 16384;
  if (j < 16384) { int n = j >> 7, kk = j & 127; W2T[j] = (bf16)W2[kk * 128 + n]; return; }
}

// ---------------- QKV projection GEMM: (4096x128)@(128x3072) ----------------
// q,k written [b][h][s][d] (q pre-scaled by 1/sqrt(D)); v written transposed [b][h][d][s].
__global__ __launch_bounds__(256, 4) void k_qkv(
    const bf16* __restrict__ xb, const bf16* __restrict__ WqkvT,
    const float* __restrict__ bq, const float* __restrict__ bk, const float* __restrict__ bv,
    bf16* __restrict__ qT, bf16* __restrict__ kT, bf16* __restrict__ vT) {
  const int bid = blockIdx.x;
  const int m0 = (bid & 63) << 6;
  const int n0 = (bid >> 6) << 6;
  const int tid = threadIdx.x;
  const int w = tid >> 6, lane = tid & 63, lo = lane & 15, hi = lane >> 4;
  const int mw = m0 + ((w >> 1) << 5);
  const int nw = n0 + ((w & 1) << 5);
  bf16x8 av[2][4], bw[2][4];
#pragma unroll
  for (int ms = 0; ms < 2; ++ms)
#pragma unroll
    for (int ks = 0; ks < 4; ++ks)
      av[ms][ks] = ld8(xb + (size_t)(mw + ms * 16 + lo) * 128 + ks * 32 + hi * 8);
#pragma unroll
  for (int ns = 0; ns < 2; ++ns)
#pragma unroll
    for (int ks = 0; ks < 4; ++ks)
      bw[ns][ks] = ld8(WqkvT + (size_t)(nw + ns * 16 + lo) * 128 + ks * 32 + hi * 8);
  const f32x4 z4 = {0.f, 0.f, 0.f, 0.f};
  f32x4 acc[2][2] = {{z4, z4}, {z4, z4}};
#pragma unroll
  for (int ms = 0; ms < 2; ++ms)
#pragma unroll
    for (int ns = 0; ns < 2; ++ns)
#pragma unroll
      for (int ks = 0; ks < 4; ++ks)
        acc[ms][ns] = mfma16(av[ms][ks], bw[ns][ks], acc[ms][ns]);
#pragma unroll
  for (int ns = 0; ns < 2; ++ns) {
    const int n = nw + ns * 16 + lo;
    const int sel = n >> 10, nn = n & 1023;
    const float bia = (sel == 0 ? bq : sel == 1 ? bk : bv)[nn];
    const int hh = nn >> 7, d = nn & 127;
#pragma unroll
    for (int ms = 0; ms < 2; ++ms) {
      const int mb = mw + ms * 16 + hi * 4;
      const int bb = mb >> 11, s = mb & 2047;
      if (sel == 0) {
#pragma unroll
        for (int r = 0; r < 4; ++r)
          qT[(size_t)((bb * 8 + hh) * 2048 + s + r) * 128 + d] =
              (bf16)((acc[ms][ns][r] + bia) * RSQRT_D);
      } else if (sel == 1) {
#pragma unroll
        for (int r = 0; r < 4; ++r)
          kT[(size_t)((bb * 8 + hh) * 2048 + s + r) * 128 + d] = (bf16)(acc[ms][ns][r] + bia);
      } else {
        ushort4 pk;
        pk.x = bfu(acc[ms][ns][0] + bia);
        pk.y = bfu(acc[ms][ns][1] + bia);
        pk.z = bfu(acc[ms][ns][2] + bia);
        pk.w = bfu(acc[ms][ns][3] + bia);
        *(ushort4*)(vT + (size_t)((bb * 8 + hh) * 128 + d) * 2048 + s) = pk;
      }
    }
  }
}

// ---------------- fused attention (v10: LDS-shared K/V, 128q block, two sweeps) ----------
// grid 256 = 16 (b,h) x 16 q-blocks of 128 rows; 512 threads = 8 waves; wave w owns q rows
// [q0+w*16, +16) and iterates ALL 2048 kv. Per 32-kv chunk the BLOCK stages K(8KB)+V(8KB)
// into LDS once (global_load_lds, double-buffered, 2 insts/wave) -> global load-insts cut
// ~4x vs per-wave loading; K staged with XOR swizzle slot^=(row&7) via PRE-SWIZZLED global
// source (LDS dest must be linear), read back conflict-free; V naturally conflict-free.
// Sweep 1: QK^T -> exp -> row sums + PV (stash transpose, proven) -> O normalized (block
// spans full kv so sums complete in-block; NO cross-wave O reduce). Sweep 2: recompute
// QK^T from staged K, scale by 1/sum, NT-store normalized attn.
__global__ __launch_bounds__(512, 2) void k_attn(
    const bf16* __restrict__ qT, const bf16* __restrict__ kT,
    const bf16* __restrict__ vT, const unsigned char* __restrict__ mask8,
    float* __restrict__ attn_out, bf16* __restrict__ Oc) {
  __shared__ __align__(16) char kbuf[2][8192];
  __shared__ __align__(16) char vbuf[2][8192];
  __shared__ __align__(16) char stash[8][1024];
  __shared__ float red2[128];

  // XCD-aware bijective swizzle: XCD x gets 32 consecutive works = exactly 2 (b,h) pairs.
  const int lbid = blockIdx.x;
  const int work = ((lbid & 7) << 5) + (lbid >> 3);
  const int bh = work >> 4;
  const int q0 = (work & 15) << 7;
  const int b = bh >> 3, h = bh & 7;
  const int tid = threadIdx.x;
  const int w = tid >> 6, lane = tid & 63, lo = lane & 15, hi = lane >> 4;

  const bf16* Qh = qT + (size_t)bh * SQ * HD;
  const bf16* Kh = kT + (size_t)bh * SQ * HD;
  const bf16* Vh = vT + (size_t)bh * HD * SQ;
  const int qg = q0 + w * 16 + lo;           // this lane's q row (col of swapped QK^T)

  // staging source addresses (chunk-invariant part). K: phys LDS (row, s) holds logical
  // slot s^(row&7)  ->  lane fetches that slot. V: linear.
  const int krow = (w << 2) + (lane >> 4);             // 0..31 within K tile
  const int kslog = (lane & 15) ^ (krow & 7);
  const bf16* kg = Kh + (size_t)krow * HD + kslog * 8;
  const int vrow = (w << 4) + (lane >> 2);             // 0..127 within V tile (d)
  const bf16* vg = Vh + (size_t)vrow * SQ + (lane & 3) * 8;

  bf16x8 qf[4];                              // 16 q rows (pre-scaled by 1/sqrt(D))
#pragma unroll
  for (int ks = 0; ks < 4; ++ks)
    qf[ks] = ld8(Qh + (size_t)qg * HD + ks * 32 + hi * 8);

  const f32x4 z4 = {0.f, 0.f, 0.f, 0.f};
  f32x4 acc[8];
#pragma unroll
  for (int ds = 0; ds < 8; ++ds) acc[ds] = z4;
  float ssum = 0.f;

  // ======== sweep 1: sums + PV ========
  gload_lds16(kg, &kbuf[0][w * 1024]);
  gload_lds16(vg, &vbuf[0][w * 1024]);
  __syncthreads();

  for (int i = 0; i < 64; ++i) {
    const int kvA = i << 5;
    const int cur = i & 1;
    if (i < 63) {
      gload_lds16(kg + (size_t)(kvA + 32) * HD, &kbuf[cur ^ 1][w * 1024]);
      gload_lds16(vg + (kvA + 32), &vbuf[cur ^ 1][w * 1024]);
    }
    const char* kb = kbuf[cur];
    const char* vb = vbuf[cur];
#pragma unroll
    for (int t = 0; t < 2; ++t) {
      const int row = t * 16 + lo;
      bf16x8 af[4];
#pragma unroll
      for (int ks = 0; ks < 4; ++ks)
        af[ks] = *(const bf16x8*)(kb + row * 256 + ((((ks << 2) + hi)) ^ (row & 7)) * 16);
      f32x4 c = z4;
#pragma unroll
      for (int ks = 0; ks < 4; ++ks) c = mfma16(af[ks], qf[ks], c);
      const unsigned mu = *(const unsigned*)(mask8 + (size_t)qg * SQ + kvA + t * 16 + hi * 4);
      float p0 = __expf(c[0] * (0.5f + 0.5f * (float)(mu & 0xff)));
      float p1 = __expf(c[1] * (0.5f + 0.5f * (float)((mu >> 8) & 0xff)));
      float p2 = __expf(c[2] * (0.5f + 0.5f * (float)((mu >> 16) & 0xff)));
      float p3 = __expf(c[3] * (0.5f + 0.5f * (float)((mu >> 24) & 0xff)));
      ssum += (p0 + p1) + (p2 + p3);
      *(uint2*)(stash[w] + lo * 64 + ((t * 32 + hi * 8) ^ ((lo & 3) << 4))) =
          make_uint2(packbf2(p0, p1), packbf2(p2, p3));
    }
    // PV over these 32 kv (same-wave stash readback; V read conflict-free linear)
    bf16x8 pa = *(const bf16x8*)(stash[w] + lo * 64 + ((hi * 16) ^ ((lo & 3) << 4)));
#pragma unroll
    for (int ds = 0; ds < 8; ++ds) {
      bf16x8 vf = *(const bf16x8*)(vb + (ds * 16 + lo) * 64 + hi * 16);
      acc[ds] = mfma16(pa, vf, acc[ds]);
    }
    __syncthreads();
  }

  // row sums complete per wave (wave saw full kv): reduce over hi, publish 1/sum
  ssum += __shfl_xor(ssum, 16);
  ssum += __shfl_xor(ssum, 32);
  if (hi == 0) red2[w * 16 + lo] = 1.0f / ssum;
  __syncthreads();

  // O write: normalized, direct from regs (no cross-wave reduce needed)
#pragma unroll
  for (int ds = 0; ds < 8; ++ds)
#pragma unroll
    for (int r = 0; r < 4; ++r) {
      const int qrow = w * 16 + hi * 4 + r;
      Oc[(size_t)(b * SQ + q0 + qrow) * (NH * HD) + h * HD + ds * 16 + lo] =
          (bf16)(acc[ds][r] * red2[qrow]);
    }

  // ======== sweep 2: recompute QK^T from staged K, write normalized attn ========
  const float rinv = red2[w * 16 + lo];
  float* abase = attn_out + (size_t)bh * SQ * SQ + (size_t)qg * SQ;
  gload_lds16(kg, &kbuf[0][w * 1024]);
  __syncthreads();
  for (int i = 0; i < 64; ++i) {
    const int kvA = i << 5;
    const int cur = i & 1;
    if (i < 63)
      gload_lds16(kg + (size_t)(kvA + 32) * HD, &kbuf[cur ^ 1][w * 1024]);
    const char* kb = kbuf[cur];
#pragma unroll
    for (int t = 0; t < 2; ++t) {
      const int row = t * 16 + lo;
      bf16x8 af[4];
#pragma unroll
      for (int ks = 0; ks < 4; ++ks)
        af[ks] = *(const bf16x8*)(kb + row * 256 + ((((ks << 2) + hi)) ^ (row & 7)) * 16);
      f32x4 c = z4;
#pragma unroll
      for (int ks = 0; ks < 4; ++ks) c = mfma16(af[ks], qf[ks], c);
      const unsigned mu = *(const unsigned*)(mask8 + (size_t)qg * SQ + kvA + t * 16 + hi * 4);
      f32x4 o;
      o[0] = __expf(c[0] * (0.5f + 0.5f * (float)(mu & 0xff))) * rinv;
      o[1] = __expf(c[1] * (0.5f + 0.5f * (float)((mu >> 8) & 0xff))) * rinv;
      o[2] = __expf(c[2] * (0.5f + 0.5f * (float)((mu >> 16) & 0xff))) * rinv;
      o[3] = __expf(c[3] * (0.5f + 0.5f * (float)((mu >> 24) & 0xff))) * rinv;
      __builtin_nontemporal_store(o, (f32x4*)(abase + kvA + t * 16 + hi * 4));
    }
    __syncthreads();
  }
}

// ---------------- out@Wo + bo + x -> LayerNorm1 -> h (f32 + bf16) ----------------
__global__ __launch_bounds__(256, 4) void k_owo(
    const bf16* __restrict__ Oc, const bf16* __restrict__ WoT,
    const float* __restrict__ bo, const float* __restrict__ x,
    const float* __restrict__ g1, const float* __restrict__ be1,
    float* __restrict__ hf, bf16* __restrict__ hb) {
  __shared__ __align__(16) float hbuf[16 * 128];
  const int m0 = blockIdx.x * 16;
  const int tid = threadIdx.x;
  const int w = tid >> 6, lane = tid & 63, lo = lane & 15, hi = lane >> 4;
  const int nw = w * 32;
  const f32x4 z4 = {0.f, 0.f, 0.f, 0.f};
  f32x4 acc[2] = {z4, z4};
#pragma unroll 4
  for (int kk = 0; kk < 32; ++kk) {
    bf16x8 a = ld8(Oc + (size_t)(m0 + lo) * 1024 + kk * 32 + hi * 8);
#pragma unroll
    for (int ns = 0; ns < 2; ++ns) {
      bf16x8 bb = ld8(WoT + (size_t)(nw + ns * 16 + lo) * 1024 + kk * 32 + hi * 8);
      acc[ns] = mfma16(a, bb, acc[ns]);
    }
  }
#pragma unroll
  for (int ns = 0; ns < 2; ++ns) {
    const int n = nw + ns * 16 + lo;
    const float bia = bo[n];
#pragma unroll
    for (int r = 0; r < 4; ++r) {
      const int mr = hi * 4 + r;
      hbuf[mr * 128 + n] = acc[ns][r] + bia + x[(size_t)(m0 + mr) * 128 + n];
    }
  }
  __syncthreads();
  const float2 g = *(const float2*)(g1 + lane * 2);
  const float2 be = *(const float2*)(be1 + lane * 2);
#pragma unroll
  for (int rr = 0; rr < 4; ++rr) {
    const int row = w * 4 + rr;
    float2 v = *(float2*)&hbuf[row * 128 + lane * 2];
    float s = v.x + v.y, sq = v.x * v.x + v.y * v.y;
#pragma unroll
    for (int off = 32; off; off >>= 1) { s += __shfl_xor(s, off); sq += __shfl_xor(sq, off); }
    const float mean = s * (1.f / 128.f);
    const float var = sq * (1.f / 128.f) - mean * mean;
    const float rstd = rsqrtf(var + 1e-5f);
    const float y0 = (v.x - mean) * rstd * g.x + be.x;
    const float y1 = (v.y - mean) * rstd * g.y + be.y;
    const size_t o = (size_t)(m0 + row) * 128 + lane * 2;
    *(float2*)(hf + o) = make_float2(y0, y1);
    *(unsigned*)(hb + o) = packbf2(y0, y1);
  }
}

// ---------------- FFN (relu(h@W1+b1)@W2+b2) + residual -> LayerNorm2 -> y ----------------
__global__ __launch_bounds__(256, 4) void k_ffn(
    const bf16* __restrict__ hb, const float* __restrict__ hf,
    const bf16* __restrict__ W1T, const bf16* __restrict__ W2T,
    const float* __restrict__ b1, const float* __restrict__ b2,
    const float* __restrict__ g2, const float* __restrict__ be2,
    float* __restrict__ yout) {
  __shared__ __align__(16) bf16 s1[16 * 136];   // +8 pad per row: conflict-free b128 rereads
  __shared__ __align__(16) float ybuf[16 * 128];
  const int m0 = blockIdx.x * 16;
  const int tid = threadIdx.x;
  const int w = tid >> 6, lane = tid & 63, lo = lane & 15, hi = lane >> 4;
  const int nw = w * 32;
  const f32x4 z4 = {0.f, 0.f, 0.f, 0.f};
  f32x4 a1[2] = {z4, z4};
#pragma unroll
  for (int kk = 0; kk < 4; ++kk) {
    bf16x8 a = ld8(hb + (size_t)(m0 + lo) * 128 + kk * 32 + hi * 8);
#pragma unroll
    for (int ns = 0; ns < 2; ++ns)
      a1[ns] = mfma16(a, ld8(W1T + (size_t)(nw + ns * 16 + lo) * 128 + kk * 32 + hi * 8), a1[ns]);
  }
#pragma unroll
  for (int ns = 0; ns < 2; ++ns) {
    const int n = nw + ns * 16 + lo;
    const float bia = b1[n];
#pragma unroll
    for (int r = 0; r < 4; ++r)
      s1[(hi * 4 + r) * 136 + n] = (bf16)fmaxf(a1[ns][r] + bia, 0.f);
  }
  __syncthreads();
  f32x4 a2[2] = {z4, z4};
#pragma unroll
  for (int kk = 0; kk < 4; ++kk) {
    bf16x8 a = *(const bf16x8*)&s1[lo * 136 + kk * 32 + hi * 8];
#pragma unroll
    for (int ns = 0; ns < 2; ++ns)
      a2[ns] = mfma16(a, ld8(W2T + (size_t)(nw + ns * 16 + lo) * 128 + kk * 32 + hi * 8), a2[ns]);
  }
#pragma unroll
  for (int ns = 0; ns < 2; ++ns) {
    const int n = nw + ns * 16 + lo;
    const float bia = b2[n];
#pragma unroll
    for (int r = 0; r < 4; ++r) {
      const int mr = hi * 4 + r;
      ybuf[mr * 128 + n] = a2[ns][r] + bia + hf[(size_t)(m0 + mr) * 128 + n];
    }
  }
  __syncthreads();
  const float2 g = *(const float2*)(g2 + lane * 2);
  const float2 be = *(const float2*)(be2 + lane * 2);
#pragma unroll
  for (int rr = 0; rr < 4; ++rr) {
    const int row = w * 4 + rr;
    float2 v = *(float2*)&ybuf[row * 128 + lane * 2];
    float s = v.x + v.y, sq = v.x * v.x + v.y * v.y;
#pragma unroll
    for (int off = 32; off; off >>= 1) { s += __shfl_xor(s, off); sq += __shfl_xor(sq, off); }
    const float mean = s * (1.f / 128.f);
    const float var = sq * (1.f / 128.f) - mean * mean;
    const float rstd = rsqrtf(var + 1e-5f);
    const float y0 = (v.x - mean) * rstd * g.x + be.x;
    const float y1 = (v.y - mean) * rstd * g.y + be.y;
    *(float2*)(yout + (size_t)(m0 + row) * 128 + lane * 2) = make_float2(y0, y1);
  }
}

extern "C" void kernel_launch(void* const* d_in, const int* in_sizes, int n_in,
                              void* d_out, int out_size, void* d_ws, size_t ws_size,
                              hipStream_t stream) {
  const float* x  = (const float*)d_in[0];
  const int* adj  = (const int*)d_in[1];
  const float* Wq = (const float*)d_in[2];  const float* bq = (const float*)d_in[3];
  const float* Wk = (const float*)d_in[4];  const float* bk = (const float*)d_in[5];
  const float* Wv = (const float*)d_in[6];  const float* bv = (const float*)d_in[7];
  const float* Wo = (const float*)d_in[8];  const float* bo = (const float*)d_in[9];
  const float* g1 = (const float*)d_in[10]; const float* be1 = (const float*)d_in[11];
  const float* g2 = (const float*)d_in[12]; const float* be2 = (const float*)d_in[13];
  const float* W1 = (const float*)d_in[14]; const float* b1 = (const float*)d_in[15];
  const float* W2 = (const float*)d_in[16]; const float* b2 = (const float*)d_in[17];

  char* ws = (char*)d_ws;
  bf16* xb     = (bf16*)(ws + 0);
  bf16* WqkvT  = (bf16*)(ws + 1048576);
  bf16* WoT    = (bf16*)(ws + 1835008);
  bf16* W1T    = (bf16*)(ws + 2097152);
  bf16* W2T    = (bf16*)(ws + 2129920);
  unsigned char* mask8 = (unsigned char*)(ws + 2162688);
  bf16* qT     = (bf16*)(ws + 6356992);
  bf16* kT     = (bf16*)(ws + 14745600);
  bf16* vT     = (bf16*)(ws + 23134208);
  bf16* Oc     = (bf16*)(ws + 31522816);
  float* hf    = (float*)(ws + 39911424);
  bf16* hb     = (bf16*)(ws + 42008576);

  float* yout = (float*)d_out;
  float* attn_out = yout + (size_t)NROWS * HD;  // y first (524288 f32), then attn

  k_prep_a<<<6144, 256, 0, stream>>>(x, adj, xb, mask8);
  k_prep_w<<<2176, 256, 0, stream>>>(Wq, Wk, Wv, Wo, W1, W2, WqkvT, WoT, W1T, W2T);
  k_qkv<<<3072, 256, 0, stream>>>(xb, WqkvT, bq, bk, bv, qT, kT, vT);
  k_attn<<<256, 512, 0, stream>>>(qT, kT, vT, mask8, attn_out, Oc);
  k_owo<<<256, 256, 0, stream>>>(Oc, WoT, bo, x, g1, be1, hf, hb);
  k_ffn<<<256, 256, 0, stream>>>(hb, hf, W1T, W2T, b1, b2, g2, be2, yout);
}

// Round 13
// 209.871 us; speedup vs baseline: 1.5307x; 1.0766x over previous
//
#include <hip/hip_runtime.h>
#include <hip/hip_bf16.h>

// ---- problem constants ----
#define HD 128          // head dim == hidden dim
#define NH 8            // heads
#define SQ 2048         // seq len
#define NROWS 4096      // B*S
#define RSQRT_D 0.08838834764831845f
#define L2EH 0.72134752044f   // 0.5 * log2(e)

typedef __bf16 bf16;
typedef bf16 bf16x8 __attribute__((ext_vector_type(8)));
typedef float f32x4 __attribute__((ext_vector_type(4)));

__device__ __forceinline__ f32x4 mfma16(bf16x8 a, bf16x8 b, f32x4 c) {
  return __builtin_amdgcn_mfma_f32_16x16x32_bf16(a, b, c, 0, 0, 0);
}
__device__ __forceinline__ bf16x8 ld8(const bf16* p) { return *(const bf16x8*)p; }
__device__ __forceinline__ unsigned short bfu(float v) {
  return __builtin_bit_cast(unsigned short, (bf16)v);
}
__device__ __forceinline__ unsigned packbf2(float a, float b) {
  return (unsigned)bfu(a) | ((unsigned)bfu(b) << 16);
}
// async global->LDS, 16B/lane; LDS dest = uniform base + lane*16 (linear);
// global src is PER-LANE (pre-swizzle the source to realize swizzled LDS layouts).
__device__ __forceinline__ void gload_lds16(const void* g, void* l) {
  __builtin_amdgcn_global_load_lds(
      (const __attribute__((address_space(1))) void*)g,
      (__attribute__((address_space(3))) void*)l, 16, 0, 0);
}

// ---------------- prep: x->bf16, adj->u8 ----------------
__global__ void k_prep_a(const float* __restrict__ x, const int* __restrict__ adj,
                         bf16* __restrict__ xb, unsigned char* __restrict__ mask8) {
  int idx = blockIdx.x * 256 + threadIdx.x;
  if (idx < NROWS * HD) { xb[idx] = (bf16)x[idx]; return; }
  int j = idx - NROWS * HD;
  if (j < (SQ * SQ / 4)) {
    int4 a = ((const int4*)adj)[j];
    uchar4 m;
    m.x = (unsigned char)a.x; m.y = (unsigned char)a.y;
    m.z = (unsigned char)a.z; m.w = (unsigned char)a.w;
    ((uchar4*)mask8)[j] = m;
  }
}

// ---------------- prep: weights -> bf16, [n][k] layout ----------------
__global__ void k_prep_w(const float* __restrict__ Wq, const float* __restrict__ Wk,
                         const float* __restrict__ Wv, const float* __restrict__ Wo,
                         const float* __restrict__ W1, const float* __restrict__ W2,
                         bf16* __restrict__ WqkvT, bf16* __restrict__ WoT,
                         bf16* __restrict__ W1T, bf16* __restrict__ W2T) {
  int idx = blockIdx.x * 256 + threadIdx.x;
  if (idx < 3072 * 128) {
    int n = idx >> 7, kk = idx & 127;
    int sel = n >> 10, nn = n & 1023;
    const float* W = (sel == 0) ? Wq : (sel == 1 ? Wk : Wv);
    WqkvT[idx] = (bf16)W[kk * 1024 + nn];
    return;
  }
  int j = idx - 3072 * 128;
  if (j < 128 * 1024) { int n = j >> 10, kk = j & 1023; WoT[j] = (bf16)Wo[kk * 128 + n]; return; }
  j -= 128 * 1024;
  if (j < 16384) { int n = j >> 7, kk = j & 127; W1T[j] = (bf16)W1[kk * 128 + n]; return; }
  j -= 16384;
  if (j < 16384) { int n = j >> 7, kk = j & 127; W2T[j] = (bf16)W2[kk * 128 + n]; return; }
}

// ---------------- QKV projection GEMM: (4096x128)@(128x3072) ----------------
// q,k written [b][h][s][d] (q pre-scaled by 1/sqrt(D)); v written transposed [b][h][d][s].
__global__ __launch_bounds__(256, 4) void k_qkv(
    const bf16* __restrict__ xb, const bf16* __restrict__ WqkvT,
    const float* __restrict__ bq, const float* __restrict__ bk, const float* __restrict__ bv,
    bf16* __restrict__ qT, bf16* __restrict__ kT, bf16* __restrict__ vT) {
  const int bid = blockIdx.x;
  const int m0 = (bid & 63) << 6;
  const int n0 = (bid >> 6) << 6;
  const int tid = threadIdx.x;
  const int w = tid >> 6, lane = tid & 63, lo = lane & 15, hi = lane >> 4;
  const int mw = m0 + ((w >> 1) << 5);
  const int nw = n0 + ((w & 1) << 5);
  bf16x8 av[2][4], bw[2][4];
#pragma unroll
  for (int ms = 0; ms < 2; ++ms)
#pragma unroll
    for (int ks = 0; ks < 4; ++ks)
      av[ms][ks] = ld8(xb + (size_t)(mw + ms * 16 + lo) * 128 + ks * 32 + hi * 8);
#pragma unroll
  for (int ns = 0; ns < 2; ++ns)
#pragma unroll
    for (int ks = 0; ks < 4; ++ks)
      bw[ns][ks] = ld8(WqkvT + (size_t)(nw + ns * 16 + lo) * 128 + ks * 32 + hi * 8);
  const f32x4 z4 = {0.f, 0.f, 0.f, 0.f};
  f32x4 acc[2][2] = {{z4, z4}, {z4, z4}};
#pragma unroll
  for (int ms = 0; ms < 2; ++ms)
#pragma unroll
    for (int ns = 0; ns < 2; ++ns)
#pragma unroll
      for (int ks = 0; ks < 4; ++ks)
        acc[ms][ns] = mfma16(av[ms][ks], bw[ns][ks], acc[ms][ns]);
#pragma unroll
  for (int ns = 0; ns < 2; ++ns) {
    const int n = nw + ns * 16 + lo;
    const int sel = n >> 10, nn = n & 1023;
    const float bia = (sel == 0 ? bq : sel == 1 ? bk : bv)[nn];
    const int hh = nn >> 7, d = nn & 127;
#pragma unroll
    for (int ms = 0; ms < 2; ++ms) {
      const int mb = mw + ms * 16 + hi * 4;
      const int bb = mb >> 11, s = mb & 2047;
      if (sel == 0) {
#pragma unroll
        for (int r = 0; r < 4; ++r)
          qT[(size_t)((bb * 8 + hh) * 2048 + s + r) * 128 + d] =
              (bf16)((acc[ms][ns][r] + bia) * RSQRT_D);
      } else if (sel == 1) {
#pragma unroll
        for (int r = 0; r < 4; ++r)
          kT[(size_t)((bb * 8 + hh) * 2048 + s + r) * 128 + d] = (bf16)(acc[ms][ns][r] + bia);
      } else {
        ushort4 pk;
        pk.x = bfu(acc[ms][ns][0] + bia);
        pk.y = bfu(acc[ms][ns][1] + bia);
        pk.z = bfu(acc[ms][ns][2] + bia);
        pk.w = bfu(acc[ms][ns][3] + bia);
        *(ushort4*)(vT + (size_t)((bb * 8 + hh) * 128 + d) * 2048 + s) = pk;
      }
    }
  }
}

// ---------------- fused attention (v11: LDS-shared K/V, 64q block, 2 blocks/CU) --------
// grid 512 = 16 (b,h) x 32 q-blocks of 64 rows; 256 threads = 4 waves; wave w owns q rows
// [q0+w*16,+16) and iterates ALL 2048 kv. Per 32-kv chunk the BLOCK stages K(8KB)+V(8KB)
// via global_load_lds (2 insts each per lane), double-buffered. 2 independent blocks/CU:
// when one block sits in its barrier vmcnt-drain, the other keeps issuing (r12 had ONE
// 8-wave block/CU -> all waves stalled together at each of the 128 barriers).
// K staged with XOR swizzle slot^=(row&7) via pre-swizzled global source; sweep 1 computes
// sums + PV (stash transpose) -> normalized O; sweep 2 recomputes QK^T from staged K,
// scales by 1/sum, NT-stores normalized attn.
__global__ __launch_bounds__(256, 2) void k_attn(
    const bf16* __restrict__ qT, const bf16* __restrict__ kT,
    const bf16* __restrict__ vT, const unsigned char* __restrict__ mask8,
    float* __restrict__ attn_out, bf16* __restrict__ Oc) {
  __shared__ __align__(16) char kbuf[2][8192];
  __shared__ __align__(16) char vbuf[2][8192];
  __shared__ __align__(16) char stash[4][1024];
  __shared__ float red2[64];

  // XCD-aware bijective swizzle: XCD x gets 64 consecutive works = exactly 2 (b,h) pairs.
  const int lbid = blockIdx.x;
  const int work = ((lbid & 7) << 6) + (lbid >> 3);
  const int bh = work >> 5;
  const int q0 = (work & 31) << 6;
  const int b = bh >> 3, h = bh & 7;
  const int tid = threadIdx.x;
  const int w = tid >> 6, lane = tid & 63, lo = lane & 15, hi = lane >> 4;

  const bf16* Qh = qT + (size_t)bh * SQ * HD;
  const bf16* Kh = kT + (size_t)bh * SQ * HD;
  const bf16* Vh = vT + (size_t)bh * HD * SQ;
  const int qg = q0 + w * 16 + lo;           // this lane's q row (col of swapped QK^T)

  // staging source addresses (chunk-invariant part), 2 gload_lds16 per lane for K and V.
  // K phys LDS (row, s) holds logical slot s^(row&7) -> lane fetches that slot.
  const int krow0 = (w << 2) + (lane >> 4);            // j=0: rows 0..15 of the 32-row tile
  const int krow1 = 16 + krow0;                        // j=1: rows 16..31
  const bf16* kg0 = Kh + (size_t)krow0 * HD + (((lane & 15) ^ (krow0 & 7)) << 3);
  const bf16* kg1 = Kh + (size_t)krow1 * HD + (((lane & 15) ^ (krow1 & 7)) << 3);
  // V linear: vbuf row = d (0..127), 64B of 32 kv per row.
  const int vrow0 = (w << 4) + (lane >> 2);            // j=0: d rows 0..63
  const int vrow1 = 64 + vrow0;                        // j=1: d rows 64..127
  const bf16* vg0 = Vh + (size_t)vrow0 * SQ + ((lane & 3) << 3);
  const bf16* vg1 = Vh + (size_t)vrow1 * SQ + ((lane & 3) << 3);

  bf16x8 qf[4];                              // 16 q rows (pre-scaled by 1/sqrt(D))
#pragma unroll
  for (int ks = 0; ks < 4; ++ks)
    qf[ks] = ld8(Qh + (size_t)qg * HD + ks * 32 + hi * 8);

  const f32x4 z4 = {0.f, 0.f, 0.f, 0.f};
  f32x4 acc[8];
#pragma unroll
  for (int ds = 0; ds < 8; ++ds) acc[ds] = z4;
  float ssum = 0.f;

  // ======== sweep 1: sums + PV ========
  gload_lds16(kg0, &kbuf[0][w * 1024]);
  gload_lds16(kg1, &kbuf[0][4096 + w * 1024]);
  gload_lds16(vg0, &vbuf[0][w * 1024]);
  gload_lds16(vg1, &vbuf[0][4096 + w * 1024]);
  __syncthreads();

  for (int i = 0; i < 64; ++i) {
    const int kvA = i << 5;
    const int cur = i & 1;
    if (i < 63) {
      const size_t ko = (size_t)(kvA + 32) * HD;
      gload_lds16(kg0 + ko, &kbuf[cur ^ 1][w * 1024]);
      gload_lds16(kg1 + ko, &kbuf[cur ^ 1][4096 + w * 1024]);
      gload_lds16(vg0 + (kvA + 32), &vbuf[cur ^ 1][w * 1024]);
      gload_lds16(vg1 + (kvA + 32), &vbuf[cur ^ 1][4096 + w * 1024]);
    }
    const char* kb = kbuf[cur];
    const char* vb = vbuf[cur];
#pragma unroll
    for (int t = 0; t < 2; ++t) {
      const int row = t * 16 + lo;
      bf16x8 af[4];
#pragma unroll
      for (int ks = 0; ks < 4; ++ks)
        af[ks] = *(const bf16x8*)(kb + row * 256 + ((((ks << 2) + hi)) ^ (row & 7)) * 16);
      f32x4 c = z4;
#pragma unroll
      for (int ks = 0; ks < 4; ++ks) c = mfma16(af[ks], qf[ks], c);
      const unsigned mu = *(const unsigned*)(mask8 + (size_t)qg * SQ + kvA + t * 16 + hi * 4);
      // exp(c*(0.5+0.5m)) = exp2(c * fma(m, L2EH, L2EH))
      float p0 = exp2f(c[0] * fmaf((float)(mu & 0xff),         L2EH, L2EH));
      float p1 = exp2f(c[1] * fmaf((float)((mu >> 8) & 0xff),  L2EH, L2EH));
      float p2 = exp2f(c[2] * fmaf((float)((mu >> 16) & 0xff), L2EH, L2EH));
      float p3 = exp2f(c[3] * fmaf((float)((mu >> 24) & 0xff), L2EH, L2EH));
      ssum += (p0 + p1) + (p2 + p3);
      *(uint2*)(stash[w] + lo * 64 + ((t * 32 + hi * 8) ^ ((lo & 3) << 4))) =
          make_uint2(packbf2(p0, p1), packbf2(p2, p3));
    }
    // PV over these 32 kv (same-wave stash readback)
    bf16x8 pa = *(const bf16x8*)(stash[w] + lo * 64 + ((hi * 16) ^ ((lo & 3) << 4)));
#pragma unroll
    for (int ds = 0; ds < 8; ++ds) {
      bf16x8 vf = *(const bf16x8*)(vb + (ds * 16 + lo) * 64 + hi * 16);
      acc[ds] = mfma16(pa, vf, acc[ds]);
    }
    __syncthreads();
  }

  // row sums complete per wave (wave saw full kv): reduce over hi, publish 1/sum
  ssum += __shfl_xor(ssum, 16);
  ssum += __shfl_xor(ssum, 32);
  if (hi == 0) red2[w * 16 + lo] = 1.0f / ssum;
  __syncthreads();

  // O write: normalized, direct from regs (no cross-wave reduce needed)
#pragma unroll
  for (int ds = 0; ds < 8; ++ds)
#pragma unroll
    for (int r = 0; r < 4; ++r) {
      const int qrow = w * 16 + hi * 4 + r;
      Oc[(size_t)(b * SQ + q0 + qrow) * (NH * HD) + h * HD + ds * 16 + lo] =
          (bf16)(acc[ds][r] * red2[qrow]);
    }

  // ======== sweep 2: recompute QK^T from staged K, write normalized attn ========
  const float rinv = red2[w * 16 + lo];
  float* abase = attn_out + (size_t)bh * SQ * SQ + (size_t)qg * SQ;
  gload_lds16(kg0, &kbuf[0][w * 1024]);
  gload_lds16(kg1, &kbuf[0][4096 + w * 1024]);
  __syncthreads();
  for (int i = 0; i < 64; ++i) {
    const int kvA = i << 5;
    const int cur = i & 1;
    if (i < 63) {
      const size_t ko = (size_t)(kvA + 32) * HD;
      gload_lds16(kg0 + ko, &kbuf[cur ^ 1][w * 1024]);
      gload_lds16(kg1 + ko, &kbuf[cur ^ 1][4096 + w * 1024]);
    }
    const char* kb = kbuf[cur];
#pragma unroll
    for (int t = 0; t < 2; ++t) {
      const int row = t * 16 + lo;
      bf16x8 af[4];
#pragma unroll
      for (int ks = 0; ks < 4; ++ks)
        af[ks] = *(const bf16x8*)(kb + row * 256 + ((((ks << 2) + hi)) ^ (row & 7)) * 16);
      f32x4 c = z4;
#pragma unroll
      for (int ks = 0; ks < 4; ++ks) c = mfma16(af[ks], qf[ks], c);
      const unsigned mu = *(const unsigned*)(mask8 + (size_t)qg * SQ + kvA + t * 16 + hi * 4);
      f32x4 o;
      o[0] = exp2f(c[0] * fmaf((float)(mu & 0xff),         L2EH, L2EH)) * rinv;
      o[1] = exp2f(c[1] * fmaf((float)((mu >> 8) & 0xff),  L2EH, L2EH)) * rinv;
      o[2] = exp2f(c[2] * fmaf((float)((mu >> 16) & 0xff), L2EH, L2EH)) * rinv;
      o[3] = exp2f(c[3] * fmaf((float)((mu >> 24) & 0xff), L2EH, L2EH)) * rinv;
      __builtin_nontemporal_store(o, (f32x4*)(abase + kvA + t * 16 + hi * 4));
    }
    __syncthreads();
  }
}

// ---------------- out@Wo + bo + x -> LayerNorm1 -> h (f32 + bf16) ----------------
__global__ __launch_bounds__(256, 4) void k_owo(
    const bf16* __restrict__ Oc, const bf16* __restrict__ WoT,
    const float* __restrict__ bo, const float* __restrict__ x,
    const float* __restrict__ g1, const float* __restrict__ be1,
    float* __restrict__ hf, bf16* __restrict__ hb) {
  __shared__ __align__(16) float hbuf[16 * 128];
  const int m0 = blockIdx.x * 16;
  const int tid = threadIdx.x;
  const int w = tid >> 6, lane = tid & 63, lo = lane & 15, hi = lane >> 4;
  const int nw = w * 32;
  const f32x4 z4 = {0.f, 0.f, 0.f, 0.f};
  f32x4 acc[2] = {z4, z4};
#pragma unroll 4
  for (int kk = 0; kk < 32; ++kk) {
    bf16x8 a = ld8(Oc + (size_t)(m0 + lo) * 1024 + kk * 32 + hi * 8);
#pragma unroll
    for (int ns = 0; ns < 2; ++ns) {
      bf16x8 bb = ld8(WoT + (size_t)(nw + ns * 16 + lo) * 1024 + kk * 32 + hi * 8);
      acc[ns] = mfma16(a, bb, acc[ns]);
    }
  }
#pragma unroll
  for (int ns = 0; ns < 2; ++ns) {
    const int n = nw + ns * 16 + lo;
    const float bia = bo[n];
#pragma unroll
    for (int r = 0; r < 4; ++r) {
      const int mr = hi * 4 + r;
      hbuf[mr * 128 + n] = acc[ns][r] + bia + x[(size_t)(m0 + mr) * 128 + n];
    }
  }
  __syncthreads();
  const float2 g = *(const float2*)(g1 + lane * 2);
  const float2 be = *(const float2*)(be1 + lane * 2);
#pragma unroll
  for (int rr = 0; rr < 4; ++rr) {
    const int row = w * 4 + rr;
    float2 v = *(float2*)&hbuf[row * 128 + lane * 2];
    float s = v.x + v.y, sq = v.x * v.x + v.y * v.y;
#pragma unroll
    for (int off = 32; off; off >>= 1) { s += __shfl_xor(s, off); sq += __shfl_xor(sq, off); }
    const float mean = s * (1.f / 128.f);
    const float var = sq * (1.f / 128.f) - mean * mean;
    const float rstd = rsqrtf(var + 1e-5f);
    const float y0 = (v.x - mean) * rstd * g.x + be.x;
    const float y1 = (v.y - mean) * rstd * g.y + be.y;
    const size_t o = (size_t)(m0 + row) * 128 + lane * 2;
    *(float2*)(hf + o) = make_float2(y0, y1);
    *(unsigned*)(hb + o) = packbf2(y0, y1);
  }
}

// ---------------- FFN (relu(h@W1+b1)@W2+b2) + residual -> LayerNorm2 -> y ----------------
__global__ __launch_bounds__(256, 4) void k_ffn(
    const bf16* __restrict__ hb, const float* __restrict__ hf,
    const bf16* __restrict__ W1T, const bf16* __restrict__ W2T,
    const float* __restrict__ b1, const float* __restrict__ b2,
    const float* __restrict__ g2, const float* __restrict__ be2,
    float* __restrict__ yout) {
  __shared__ __align__(16) bf16 s1[16 * 136];   // +8 pad per row: conflict-free b128 rereads
  __shared__ __align__(16) float ybuf[16 * 128];
  const int m0 = blockIdx.x * 16;
  const int tid = threadIdx.x;
  const int w = tid >> 6, lane = tid & 63, lo = lane & 15, hi = lane >> 4;
  const int nw = w * 32;
  const f32x4 z4 = {0.f, 0.f, 0.f, 0.f};
  f32x4 a1[2] = {z4, z4};
#pragma unroll
  for (int kk = 0; kk < 4; ++kk) {
    bf16x8 a = ld8(hb + (size_t)(m0 + lo) * 128 + kk * 32 + hi * 8);
#pragma unroll
    for (int ns = 0; ns < 2; ++ns)
      a1[ns] = mfma16(a, ld8(W1T + (size_t)(nw + ns * 16 + lo) * 128 + kk * 32 + hi * 8), a1[ns]);
  }
#pragma unroll
  for (int ns = 0; ns < 2; ++ns) {
    const int n = nw + ns * 16 + lo;
    const float bia = b1[n];
#pragma unroll
    for (int r = 0; r < 4; ++r)
      s1[(hi * 4 + r) * 136 + n] = (bf16)fmaxf(a1[ns][r] + bia, 0.f);
  }
  __syncthreads();
  f32x4 a2[2] = {z4, z4};
#pragma unroll
  for (int kk = 0; kk < 4; ++kk) {
    bf16x8 a = *(const bf16x8*)&s1[lo * 136 + kk * 32 + hi * 8];
#pragma unroll
    for (int ns = 0; ns < 2; ++ns)
      a2[ns] = mfma16(a, ld8(W2T + (size_t)(nw + ns * 16 + lo) * 128 + kk * 32 + hi * 8), a2[ns]);
  }
#pragma unroll
  for (int ns = 0; ns < 2; ++ns) {
    const int n = nw + ns * 16 + lo;
    const float bia = b2[n];
#pragma unroll
    for (int r = 0; r < 4; ++r) {
      const int mr = hi * 4 + r;
      ybuf[mr * 128 + n] = a2[ns][r] + bia + hf[(size_t)(m0 + mr) * 128 + n];
    }
  }
  __syncthreads();
  const float2 g = *(const float2*)(g2 + lane * 2);
  const float2 be = *(const float2*)(be2 + lane * 2);
#pragma unroll
  for (int rr = 0; rr < 4; ++rr) {
    const int row = w * 4 + rr;
    float2 v = *(float2*)&ybuf[row * 128 + lane * 2];
    float s = v.x + v.y, sq = v.x * v.x + v.y * v.y;
#pragma unroll
    for (int off = 32; off; off >>= 1) { s += __shfl_xor(s, off); sq += __shfl_xor(sq, off); }
    const float mean = s * (1.f / 128.f);
    const float var = sq * (1.f / 128.f) - mean * mean;
    const float rstd = rsqrtf(var + 1e-5f);
    const float y0 = (v.x - mean) * rstd * g.x + be.x;
    const float y1 = (v.y - mean) * rstd * g.y + be.y;
    *(float2*)(yout + (size_t)(m0 + row) * 128 + lane * 2) = make_float2(y0, y1);
  }
}

extern "C" void kernel_launch(void* const* d_in, const int* in_sizes, int n_in,
                              void* d_out, int out_size, void* d_ws, size_t ws_size,
                              hipStream_t stream) {
  const float* x  = (const float*)d_in[0];
  const int* adj  = (const int*)d_in[1];
  const float* Wq = (const float*)d_in[2];  const float* bq = (const float*)d_in[3];
  const float* Wk = (const float*)d_in[4];  const float* bk = (const float*)d_in[5];
  const float* Wv = (const float*)d_in[6];  const float* bv = (const float*)d_in[7];
  const float* Wo = (const float*)d_in[8];  const float* bo = (const float*)d_in[9];
  const float* g1 = (const float*)d_in[10]; const float* be1 = (const float*)d_in[11];
  const float* g2 = (const float*)d_in[12]; const float* be2 = (const float*)d_in[13];
  const float* W1 = (const float*)d_in[14]; const float* b1 = (const float*)d_in[15];
  const float* W2 = (const float*)d_in[16]; const float* b2 = (const float*)d_in[17];

  char* ws = (char*)d_ws;
  bf16* xb     = (bf16*)(ws + 0);
  bf16* WqkvT  = (bf16*)(ws + 1048576);
  bf16* WoT    = (bf16*)(ws + 1835008);
  bf16* W1T    = (bf16*)(ws + 2097152);
  bf16* W2T    = (bf16*)(ws + 2129920);
  unsigned char* mask8 = (unsigned char*)(ws + 2162688);
  bf16* qT     = (bf16*)(ws + 6356992);
  bf16* kT     = (bf16*)(ws + 14745600);
  bf16* vT     = (bf16*)(ws + 23134208);
  bf16* Oc     = (bf16*)(ws + 31522816);
  float* hf    = (float*)(ws + 39911424);
  bf16* hb     = (bf16*)(ws + 42008576);

  float* yout = (float*)d_out;
  float* attn_out = yout + (size_t)NROWS * HD;  // y first (524288 f32), then attn

  k_prep_a<<<6144, 256, 0, stream>>>(x, adj, xb, mask8);
  k_prep_w<<<2176, 256, 0, stream>>>(Wq, Wk, Wv, Wo, W1, W2, WqkvT, WoT, W1T, W2T);
  k_qkv<<<3072, 256, 0, stream>>>(xb, WqkvT, bq, bk, bv, qT, kT, vT);
  k_attn<<<512, 256, 0, stream>>>(qT, kT, vT, mask8, attn_out, Oc);
  k_owo<<<256, 256, 0, stream>>>(Oc, WoT, bo, x, g1, be1, hf, hb);
  k_ffn<<<256, 256, 0, stream>>>(hb, hf, W1T, W2T, b1, b2, g2, be2, yout);
}